// Round 3
// baseline (650.186 us; speedup 1.0000x reference)
//
#include <hip/hip_runtime.h>
#include <hip/hip_bf16.h>

// Problem constants
#define Bn 128
#define Tn 64
#define Dn 1024
#define Hn 16
#define HDn 64

typedef __bf16 bf16_t;
typedef __bf16 bf16x8 __attribute__((ext_vector_type(8)));
typedef float f32x4 __attribute__((ext_vector_type(4)));

__device__ __forceinline__ f32x4 mfma16(bf16x8 a, bf16x8 b, f32x4 c) {
  return __builtin_amdgcn_mfma_f32_16x16x32_bf16(a, b, c, 0, 0, 0);
}

// load 8 consecutive fp32, round to bf16 fragment
__device__ __forceinline__ bf16x8 ld8f(const float* p) {
  float4 a = *(const float4*)p;
  float4 b = *(const float4*)(p + 4);
  bf16x8 r;
  r[0] = (bf16_t)a.x; r[1] = (bf16_t)a.y; r[2] = (bf16_t)a.z; r[3] = (bf16_t)a.w;
  r[4] = (bf16_t)b.x; r[5] = (bf16_t)b.y; r[6] = (bf16_t)b.z; r[7] = (bf16_t)b.w;
  return r;
}

// ---------------------------------------------------------------------------
// K-1: fp32 -> bf16 bulk convert (for x). 8 elems/thread.
// ---------------------------------------------------------------------------
__global__ __launch_bounds__(256) void convert_bf16(const float* __restrict__ src,
                                                    bf16_t* __restrict__ dst) {
  long i = ((long)blockIdx.x * 256 + threadIdx.x) * 8;
  *(bf16x8*)(dst + i) = ld8f(src + i);
}

// ---------------------------------------------------------------------------
// K0: 1024x1024 transpose + fp32->bf16 (weights): Wt[n][k] = W[k][n]
// ---------------------------------------------------------------------------
__global__ __launch_bounds__(256) void transpose_mat(const float* __restrict__ W,
                                                     bf16_t* __restrict__ Wt) {
  __shared__ bf16_t tile[64][65];
  const int tr = blockIdx.y, tc = blockIdx.x;
  const int t = threadIdx.x;
#pragma unroll
  for (int i = 0; i < 16; i++) {
    int idx = t + i * 256;
    int r = idx >> 6, c = idx & 63;
    tile[r][c] = (bf16_t)W[(long)(tr * 64 + r) * 1024 + tc * 64 + c];
  }
  __syncthreads();
#pragma unroll
  for (int i = 0; i < 16; i++) {
    int idx = t + i * 256;
    int c = idx >> 6, r = idx & 63;
    Wt[(long)(tc * 64 + c) * 1024 + tr * 64 + r] = tile[r][c];
  }
}

// ---------------------------------------------------------------------------
// K1/K5: C[M,N] = A[M,K] @ Bt[N,K]^T  (bf16 in, fp32 acc, CT out)
// 128x128 tile, BK=64, 4 waves each computing a 64x64 quadrant.
// ---------------------------------------------------------------------------
template <typename CT>
__global__ __launch_bounds__(256) void gemm_bt(const bf16_t* __restrict__ A,
                                               const bf16_t* __restrict__ Bt,
                                               CT* __restrict__ C,
                                               int M, int N, int K) {
  __shared__ bf16_t As[128 * 64];
  __shared__ bf16_t Bs[128 * 64];
  const int t = threadIdx.x;
  const int w = t >> 6, lane = t & 63;
  const int l16 = lane & 15, quad = lane >> 4;
  const int m0 = blockIdx.y * 128, n0 = blockIdx.x * 128;
  const int wm = (w >> 1) * 64, wn = (w & 1) * 64;

  f32x4 acc[4][4];
#pragma unroll
  for (int i = 0; i < 4; i++)
#pragma unroll
    for (int j = 0; j < 4; j++) acc[i][j] = (f32x4){0.f, 0.f, 0.f, 0.f};

  const int sr = t >> 3;         // 0..31: row within 32-row group
  const int sc = (t & 7) * 8;    // col (element) within 64

  for (int k0 = 0; k0 < K; k0 += 64) {
    __syncthreads();
#pragma unroll
    for (int i = 0; i < 4; i++) {
      int row = i * 32 + sr;
      *(bf16x8*)(As + row * 64 + sc) =
          *(const bf16x8*)(A + (long)(m0 + row) * K + k0 + sc);
      *(bf16x8*)(Bs + row * 64 + sc) =
          *(const bf16x8*)(Bt + (long)(n0 + row) * K + k0 + sc);
    }
    __syncthreads();
#pragma unroll
    for (int kk = 0; kk < 64; kk += 32) {
      bf16x8 af[4], bfr[4];
#pragma unroll
      for (int i = 0; i < 4; i++)
        af[i] = *(const bf16x8*)(As + (wm + i * 16 + l16) * 64 + kk + quad * 8);
#pragma unroll
      for (int j = 0; j < 4; j++)
        bfr[j] = *(const bf16x8*)(Bs + (wn + j * 16 + l16) * 64 + kk + quad * 8);
#pragma unroll
      for (int i = 0; i < 4; i++)
#pragma unroll
        for (int j = 0; j < 4; j++) acc[i][j] = mfma16(af[i], bfr[j], acc[i][j]);
    }
  }
#pragma unroll
  for (int i = 0; i < 4; i++)
#pragma unroll
    for (int j = 0; j < 4; j++) {
      int col = n0 + wn + j * 16 + l16;
#pragma unroll
      for (int r = 0; r < 4; r++) {
        int row = m0 + wm + i * 16 + quad * 4 + r;
        C[(long)row * N + col] = (CT)acc[i][j][r];
      }
    }
}

// ---------------------------------------------------------------------------
// K2a: content logits. block = (h, b). logits[b,h,q,k] = scale * Q_h @ K_h^T
// ---------------------------------------------------------------------------
__global__ __launch_bounds__(256) void logits_cc(const bf16_t* __restrict__ Q,
                                                 const bf16_t* __restrict__ Km,
                                                 float* __restrict__ logits) {
  const int h = blockIdx.x, b = blockIdx.y;
  const int t = threadIdx.x, w = t >> 6, lane = t & 63;
  const int l16 = lane & 15, quad = lane >> 4;
  const bf16_t* qbase = Q + (long)b * (Tn * Dn) + h * HDn;
  const bf16_t* kbase = Km + (long)b * (Tn * Dn) + h * HDn;
  f32x4 acc[4];
#pragma unroll
  for (int j = 0; j < 4; j++) acc[j] = (f32x4){0.f, 0.f, 0.f, 0.f};
#pragma unroll
  for (int kk = 0; kk < 64; kk += 32) {
    bf16x8 af = *(const bf16x8*)(qbase + (long)(w * 16 + l16) * Dn + kk + quad * 8);
#pragma unroll
    for (int j = 0; j < 4; j++) {
      bf16x8 bfr = *(const bf16x8*)(kbase + (long)(j * 16 + l16) * Dn + kk + quad * 8);
      acc[j] = mfma16(af, bfr, acc[j]);
    }
  }
  float* lb = logits + ((long)(b * Hn + h) * Tn) * Tn;
#pragma unroll
  for (int j = 0; j < 4; j++)
#pragma unroll
    for (int r = 0; r < 4; r++) {
      int q = w * 16 + quad * 4 + r, k = j * 16 + l16;
      lb[q * 64 + k] = acc[j][r] * 0.125f;
    }
}

// ---------------------------------------------------------------------------
// K2b: logits[b,h,q,k] += sum_d a_q[b,q,k,d] * K[b,k,h,d].  wave per k.
// a_q read as fp32, converted inline.
// ---------------------------------------------------------------------------
__global__ __launch_bounds__(256) void logits_aq(const float* __restrict__ aqp,
                                                 const bf16_t* __restrict__ Km,
                                                 float* __restrict__ logits) {
  const int b = blockIdx.y;
  const int kfix = blockIdx.x * 4 + (threadIdx.x >> 6);
  const int lane = threadIdx.x & 63, l16 = lane & 15, quad = lane >> 4;
  const float* abase = aqp + (long)b * (Tn * Tn * HDn) + kfix * HDn;  // + q*4096 + d
  const bf16_t* bbase = Km + (long)(b * Tn + kfix) * Dn;              // + h*64 + d
  f32x4 acc[4];
#pragma unroll
  for (int i = 0; i < 4; i++) acc[i] = (f32x4){0.f, 0.f, 0.f, 0.f};
#pragma unroll
  for (int kk = 0; kk < 64; kk += 32) {
    bf16x8 bfr = *(const bf16x8*)(bbase + l16 * 64 + kk + quad * 8);
#pragma unroll
    for (int i = 0; i < 4; i++) {
      bf16x8 af = ld8f(abase + (long)(i * 16 + l16) * (Tn * HDn) + kk + quad * 8);
      acc[i] = mfma16(af, bfr, acc[i]);
    }
  }
  // acc[i][r] is [q = i*16+quad*4+r][h = l16]
  float* lb = logits + (long)b * (Hn * Tn * Tn) + kfix;  // + h*T*T + q*T
#pragma unroll
  for (int i = 0; i < 4; i++)
#pragma unroll
    for (int r = 0; r < 4; r++) {
      int q = i * 16 + quad * 4 + r, h = l16;
      lb[(long)h * (Tn * Tn) + q * Tn] += acc[i][r];
    }
}

// ---------------------------------------------------------------------------
// K2c: logits[b,h,q,k] += sum_d Q[b,q,h,d] * a_k[b,q,k,d].  wave per q.
// a_k read as fp32, converted inline.
// ---------------------------------------------------------------------------
__global__ __launch_bounds__(256) void logits_ak(const bf16_t* __restrict__ Q,
                                                 const float* __restrict__ akp,
                                                 float* __restrict__ logits) {
  const int b = blockIdx.y;
  const int q = blockIdx.x * 4 + (threadIdx.x >> 6);
  const int lane = threadIdx.x & 63, l16 = lane & 15, quad = lane >> 4;
  const bf16_t* abase = Q + (long)(b * Tn + q) * Dn;                  // + h*64 + d
  const float* bbase = akp + (long)(b * Tn + q) * (Tn * HDn);         // + k*64 + d
  f32x4 acc[4];
#pragma unroll
  for (int j = 0; j < 4; j++) acc[j] = (f32x4){0.f, 0.f, 0.f, 0.f};
#pragma unroll
  for (int kk = 0; kk < 64; kk += 32) {
    bf16x8 af = *(const bf16x8*)(abase + l16 * 64 + kk + quad * 8);
#pragma unroll
    for (int j = 0; j < 4; j++) {
      bf16x8 bfr = ld8f(bbase + (long)(j * 16 + l16) * 64 + kk + quad * 8);
      acc[j] = mfma16(af, bfr, acc[j]);
    }
  }
  // acc[j][r] is [h = quad*4+r][k = j*16+l16]
  float* lb = logits + (long)b * (Hn * Tn * Tn) + q * 64;  // + h*4096 + k
#pragma unroll
  for (int j = 0; j < 4; j++)
#pragma unroll
    for (int r = 0; r < 4; r++) {
      int h = quad * 4 + r, k = j * 16 + l16;
      lb[(long)h * (Tn * Tn) + k] += acc[j][r];
    }
}

// ---------------------------------------------------------------------------
// K3: per (b,q): softmax over k per head from fp32 logits,
//     write probs (bf16) and out2[b,q,h,d] = probs @ a_v[b,q]
// ---------------------------------------------------------------------------
__global__ __launch_bounds__(256) void softmax_pav(const float* __restrict__ logits,
                                                   const float* __restrict__ avp,
                                                   bf16_t* __restrict__ probs,
                                                   bf16_t* __restrict__ out2) {
  const int q = blockIdx.x, b = blockIdx.y;
  __shared__ bf16_t pl[16][72];
  __shared__ bf16_t avT[64][72];
  const int t = threadIdx.x, w = t >> 6, lane = t & 63;
  const int l16 = lane & 15, quad = lane >> 4;

  {  // a_v[b,q,k,d] (fp32) -> avT[d][k] (bf16)
    const float* src = avp + (long)(b * Tn + q) * (Tn * HDn);
    int k = t >> 2, d0 = (t & 3) * 16;
    unsigned short* lds = (unsigned short*)&avT[0][0];
#pragma unroll
    for (int c = 0; c < 4; c++) {
      float4 v = *(const float4*)(src + k * 64 + d0 + c * 4);
      bf16_t e0 = (bf16_t)v.x, e1 = (bf16_t)v.y, e2 = (bf16_t)v.z, e3 = (bf16_t)v.w;
      lds[(d0 + c * 4 + 0) * 72 + k] = *(unsigned short*)&e0;
      lds[(d0 + c * 4 + 1) * 72 + k] = *(unsigned short*)&e1;
      lds[(d0 + c * 4 + 2) * 72 + k] = *(unsigned short*)&e2;
      lds[(d0 + c * 4 + 3) * 72 + k] = *(unsigned short*)&e3;
    }
  }

  const int k = lane;
#pragma unroll
  for (int i = 0; i < 4; i++) {
    int h = w * 4 + i;
    float val = logits[((long)(b * Hn + h) * Tn + q) * Tn + k];
    float m = val;
#pragma unroll
    for (int off = 32; off; off >>= 1) m = fmaxf(m, __shfl_xor(m, off));
    float e = __expf(val - m);
    float s = e;
#pragma unroll
    for (int off = 32; off; off >>= 1) s += __shfl_xor(s, off);
    float p = e / s;
    bf16_t pb = (bf16_t)p;
    probs[((long)(b * Hn + h) * Tn + q) * Tn + k] = pb;
    pl[h][k] = pb;
  }
  __syncthreads();

  // out2[h, d-tile w]: A = pl[h][k], Bt = avT[d][k]
  f32x4 acc = (f32x4){0.f, 0.f, 0.f, 0.f};
#pragma unroll
  for (int kk = 0; kk < 64; kk += 32) {
    bf16x8 af = *(const bf16x8*)(&pl[l16][kk + quad * 8]);
    bf16x8 bfr = *(const bf16x8*)(&avT[w * 16 + l16][kk + quad * 8]);
    acc = mfma16(af, bfr, acc);
  }
  bf16_t* ob = out2 + (long)(b * Tn + q) * Dn;
#pragma unroll
  for (int r = 0; r < 4; r++) {
    int h = quad * 4 + r, d = w * 16 + l16;
    ob[h * 64 + d] = (bf16_t)acc[r];
  }
}

// ---------------------------------------------------------------------------
// K4: per (b,h): attn[b,q,h,d] = probs[b,h] @ V[b,:,h,:] + out2[b,q,h,d]
// ---------------------------------------------------------------------------
__global__ __launch_bounds__(256) void pv_out(const bf16_t* __restrict__ probs,
                                              const bf16_t* __restrict__ V,
                                              const bf16_t* __restrict__ out2,
                                              bf16_t* __restrict__ attn) {
  const int h = blockIdx.x, b = blockIdx.y;
  __shared__ bf16_t VT[64][72];
  const int t = threadIdx.x, w = t >> 6, lane = t & 63;
  const int l16 = lane & 15, quad = lane >> 4;

  {  // V[b,k,h,d] -> VT[d][k]
    const bf16_t* src = V + (long)b * (Tn * Dn) + h * HDn;
    int k = t & 63, d0 = (t >> 6) * 16;
    union { uint4 u; unsigned short s[8]; } v0, v1;
    v0.u = *(const uint4*)(src + (long)k * Dn + d0);
    v1.u = *(const uint4*)(src + (long)k * Dn + d0 + 8);
    unsigned short* lds = (unsigned short*)&VT[0][0];
#pragma unroll
    for (int j = 0; j < 8; j++) lds[(d0 + j) * 72 + k] = v0.s[j];
#pragma unroll
    for (int j = 0; j < 8; j++) lds[(d0 + 8 + j) * 72 + k] = v1.s[j];
  }
  __syncthreads();

  const bf16_t* pbase = probs + ((long)(b * Hn + h) * Tn) * Tn;
  f32x4 acc[4];
#pragma unroll
  for (int j = 0; j < 4; j++) acc[j] = (f32x4){0.f, 0.f, 0.f, 0.f};
#pragma unroll
  for (int kk = 0; kk < 64; kk += 32) {
    bf16x8 af = *(const bf16x8*)(pbase + (long)(w * 16 + l16) * Tn + kk + quad * 8);
#pragma unroll
    for (int j = 0; j < 4; j++) {
      bf16x8 bfr = *(const bf16x8*)(&VT[j * 16 + l16][kk + quad * 8]);
      acc[j] = mfma16(af, bfr, acc[j]);
    }
  }
#pragma unroll
  for (int j = 0; j < 4; j++)
#pragma unroll
    for (int r = 0; r < 4; r++) {
      int qrow = w * 16 + quad * 4 + r, d = j * 16 + l16;
      long idx = (long)(b * Tn + qrow) * Dn + h * HDn + d;
      attn[idx] = (bf16_t)(acc[j][r] + (float)out2[idx]);
    }
}

// ---------------------------------------------------------------------------
extern "C" void kernel_launch(void* const* d_in, const int* in_sizes, int n_in,
                              void* d_out, int out_size, void* d_ws, size_t ws_size,
                              hipStream_t stream) {
  const float* x  = (const float*)d_in[0];
  const float* aq = (const float*)d_in[1];
  const float* ak = (const float*)d_in[2];
  const float* av = (const float*)d_in[3];
  const float* Wq = (const float*)d_in[4];
  const float* Wk = (const float*)d_in[5];
  const float* Wv = (const float*)d_in[6];
  const float* Wo = (const float*)d_in[7];
  float* out = (float*)d_out;

  char* ws = (char*)d_ws;
  const size_t MB = 1024 * 1024;
  bf16_t* WqT    = (bf16_t*)(ws + 0 * MB);     // 2MB each
  bf16_t* WkT    = (bf16_t*)(ws + 2 * MB);
  bf16_t* WvT    = (bf16_t*)(ws + 4 * MB);
  bf16_t* WoT    = (bf16_t*)(ws + 6 * MB);
  bf16_t* xb     = (bf16_t*)(ws + 8 * MB);     // [B,T,D] bf16 16MB
  bf16_t* Qb     = (bf16_t*)(ws + 24 * MB);    // [B,T,H,HD] 16MB
  bf16_t* Kb     = (bf16_t*)(ws + 40 * MB);
  bf16_t* Vb     = (bf16_t*)(ws + 56 * MB);
  float*  logits = (float*)(ws + 72 * MB);     // [B,H,T,T] fp32 32MB
  bf16_t* probs  = (bf16_t*)(ws + 104 * MB);   // [B,H,T,T] 16MB
  bf16_t* out2   = (bf16_t*)(ws + 120 * MB);   // [B,T,H,HD] 16MB
  bf16_t* attn   = (bf16_t*)(ws + 136 * MB);   // [B,T,D] 16MB -> 152MB total

  dim3 blk(256);
  convert_bf16<<<dim3(4096), blk, 0, stream>>>(x, xb);  // 8192*1024 / (256*8)
  transpose_mat<<<dim3(16, 16), blk, 0, stream>>>(Wq, WqT);
  transpose_mat<<<dim3(16, 16), blk, 0, stream>>>(Wk, WkT);
  transpose_mat<<<dim3(16, 16), blk, 0, stream>>>(Wv, WvT);
  transpose_mat<<<dim3(16, 16), blk, 0, stream>>>(Wo, WoT);

  gemm_bt<bf16_t><<<dim3(8, 64), blk, 0, stream>>>(xb, WqT, Qb, Bn * Tn, Dn, Dn);
  gemm_bt<bf16_t><<<dim3(8, 64), blk, 0, stream>>>(xb, WkT, Kb, Bn * Tn, Dn, Dn);
  gemm_bt<bf16_t><<<dim3(8, 64), blk, 0, stream>>>(xb, WvT, Vb, Bn * Tn, Dn, Dn);

  logits_cc<<<dim3(Hn, Bn), blk, 0, stream>>>(Qb, Kb, logits);
  logits_aq<<<dim3(16, Bn), blk, 0, stream>>>(aq, Kb, logits);
  logits_ak<<<dim3(16, Bn), blk, 0, stream>>>(Qb, ak, logits);

  softmax_pav<<<dim3(Tn, Bn), blk, 0, stream>>>(logits, av, probs, out2);
  pv_out<<<dim3(Hn, Bn), blk, 0, stream>>>(probs, Vb, out2, attn);

  gemm_bt<float><<<dim3(8, 64), blk, 0, stream>>>(attn, WoT, out, Bn * Tn, Dn, Dn);
}